// Round 5
// baseline (143.093 us; speedup 1.0000x reference)
//
#include <hip/hip_runtime.h>
#include <hip/hip_cooperative_groups.h>

namespace cg = cooperative_groups;

#define T_HOR  5
#define MAXIT  100
#define NFLAGS 12
#define EPSC   0.01f

// One LQR sweep for ONE 2-state subsystem (p' = p + 0.1 v, v' = 0.75 v + 0.5(ua-ub)).
// All t-loops statically unrolled (register indexing); callers keep the
// iteration loops ROLLED (#pragma unroll 1 + runtime bounds) so the hot loop
// stays ~1.4 KB and lives in I-cache.
__device__ __forceinline__ float iter_once(
    const float (&c0)[T_HOR], const float (&c1)[T_HOR],
    const float (&gp)[T_HOR], const float (&hp)[T_HOR],
    float xi_p, float xi_v, float pc_p, float pc_v,
    float (&ua)[T_HOR], float (&ub)[T_HOR])
{
    // rollout
    float xp[T_HOR], xv[T_HOR];
    xp[0] = xi_p; xv[0] = xi_v;
    #pragma unroll
    for (int t = 0; t < T_HOR-1; ++t) {
        xp[t+1] = xp[t] + 0.1f*xv[t];
        xv[t+1] = 0.75f*xv[t] + 0.5f*(ua[t]-ub[t]);
    }

    // backward affine pass (quadratic Riccati part is compile-time constant)
    float ka[T_HOR], kb[T_HOR];
    float vp = 0.f, vv = 0.f;
    #pragma unroll
    for (int t = T_HOR-1; t >= 0; --t) {
        float qa = 0.01f + 0.1f*ua[t] + 0.5f*vv;
        float qb = 0.01f + 0.1f*ub[t] - 0.5f*vv;
        ka[t] = -(c0[t]*qa + c1[t]*qb);
        kb[t] = -(c1[t]*qa + c0[t]*qb);
        float qxp = (pc_p + xp[t]) + vp;
        float qxv = (pc_v + 0.1f*xv[t]) + 0.1f*vp + 0.75f*vv;
        float dq = qa - qb;
        vp = qxp - gp[t]*dq;
        vv = qxv - hp[t]*dq;
    }

    // forward pass with clip
    float delta = 0.f, dp = 0.f, dv = 0.f;
    #pragma unroll
    for (int t = 0; t < T_HOR; ++t) {
        float phi = gp[t]*dp + hp[t]*dv;
        float na = fminf(fmaxf(ua[t] + (ka[t] - phi), 0.f), 1.f);
        float nb = fminf(fmaxf(ub[t] + (kb[t] + phi), 0.f), 1.f);
        float dua = na - ua[t], dub = nb - ub[t];
        delta = fmaxf(delta, fmaxf(fabsf(dua), fabsf(dub)));
        float ndp = dp + 0.1f*dv;
        float ndv = 0.75f*dv + 0.5f*(dua - dub);
        dp = ndp; dv = ndv;
        ua[t] = na; ub[t] = nb;
    }
    return delta;
}

__global__ __launch_bounds__(256)
void mpc_iter_kernel(const float* __restrict__ x_init,
                     const float* __restrict__ xd,
                     float2* __restrict__ out,
                     int* __restrict__ flags,
                     int g0len, int glen)   // runtime args -> loops can't unroll
{
    cg::grid_group grid = cg::this_grid();
    const int tid = blockIdx.x * 256 + threadIdx.x;
    const int b = tid >> 1;      // batch element
    const int s = tid & 1;       // subsystem 0: (p1,v1,u0,u1)  1: (p2,v2,u2,u3)

    // in-kernel workspace zeroing; made globally visible by the first grid.sync
    if (tid == 0) {
        #pragma unroll
        for (int g = 0; g < NFLAGS; ++g) flags[g] = 0;
    }

    const float SQ01 = 0.31622776601683794f;  // sqrt(0.1)
    const float xi_p = x_init[4*b + s];
    const float xi_v = x_init[4*b + 2 + s];
    const float pc_p = -xd[4*b + s];
    const float pc_v = -SQ01 * xd[4*b + 2 + s];

    // Batch-independent Riccati gain schedule (constant-folds at compile time)
    float c0[T_HOR], c1[T_HOR], gp[T_HOR], hp[T_HOR];
    {
        float Vpp = 0.f, Vpv = 0.f, Vvv = 0.f;
        #pragma unroll
        for (int t = T_HOR-1; t >= 0; --t) {
            float ss = 0.25f * Vvv;
            float tw = 0.1f + 2.f*ss;
            float dd = 0.1f * tw;
            c0[t] = (0.1f + ss) / dd;
            c1[t] = ss / dd;
            float g = 0.5f * Vpv;
            float h = 0.05f * Vpv + 0.375f * Vvv;
            float inv = 1.f / tw;
            gp[t] = g * inv;
            hp[t] = h * inv;
            float nVpp = 1.0f + Vpp - 2.f*g*gp[t];
            float nVpv = 0.1f*Vpp + 0.75f*Vpv - 2.f*g*hp[t];
            float nVvv = 0.1f + 0.01f*Vpp + 0.15f*Vpv + 0.5625f*Vvv - 2.f*h*hp[t];
            Vpp = nVpp; Vpv = nVpv; Vvv = nVvv;
        }
    }

    float ua[T_HOR] = {0,0,0,0,0}, ub[T_HOR] = {0,0,0,0,0};

    // ---- group 0: g0len iterations, convergence bitmask, then 2 syncs
    unsigned mask = 0u;
    #pragma unroll 1
    for (int j = 0; j < g0len; ++j) {
        float d = iter_once(c0, c1, gp, hp, xi_p, xi_v, pc_p, pc_v, ua, ub);
        mask |= (d > EPSC ? 1u : 0u) << j;
    }
    int bor = __syncthreads_or((int)mask);
    grid.sync();   // flag zeroing visible everywhere before any atomicOr
    if (threadIdx.x == 0 && bor) {
        __hip_atomic_fetch_or(&flags[0], bor, __ATOMIC_RELEASE, __HIP_MEMORY_SCOPE_AGENT);
    }
    grid.sync();
    unsigned gm = (unsigned)__hip_atomic_load(&flags[0], __ATOMIC_ACQUIRE, __HIP_MEMORY_SCOPE_AGENT);
    int j0 = (int)__builtin_ctz(~gm);   // bits >= g0len are 0 -> j0 <= g0len

    bool done = false;
    if (j0 < g0len) {
        // cold path (n* <= g0len): replay j0+1 iterations from zeros
        #pragma unroll
        for (int t = 0; t < T_HOR; ++t) { ua[t] = 0.f; ub[t] = 0.f; }
        #pragma unroll 1
        for (int j = 0; j <= j0; ++j)
            iter_once(c0, c1, gp, hp, xi_p, xi_v, pc_p, pc_v, ua, ub);
        done = true;
    }

    // ---- tail groups of glen: checkpoint, iterate, one sync, replay if stop
    if (!done) {
        int it_base = g0len;
        #pragma unroll 1
        for (int g = 1; it_base < MAXIT; ++g) {
            int gl = glen < (MAXIT - it_base) ? glen : (MAXIT - it_base);
            float ck0[T_HOR], ck1[T_HOR];
            #pragma unroll
            for (int t = 0; t < T_HOR; ++t) { ck0[t] = ua[t]; ck1[t] = ub[t]; }

            unsigned msk = 0u;
            #pragma unroll 1
            for (int j = 0; j < gl; ++j) {
                float d = iter_once(c0, c1, gp, hp, xi_p, xi_v, pc_p, pc_v, ua, ub);
                msk |= (d > EPSC ? 1u : 0u) << j;
            }
            int m = __syncthreads_or((int)msk);
            if (threadIdx.x == 0 && m) {
                __hip_atomic_fetch_or(&flags[g], m, __ATOMIC_RELEASE, __HIP_MEMORY_SCOPE_AGENT);
            }
            grid.sync();
            unsigned gmt = (unsigned)__hip_atomic_load(&flags[g], __ATOMIC_ACQUIRE, __HIP_MEMORY_SCOPE_AGENT);
            int jj = (int)__builtin_ctz(~gmt);   // bits >= gl are 0 -> jj <= gl
            if (jj < gl) {
                // global stop at iteration it_base+jj+1: restore + replay
                #pragma unroll
                for (int t = 0; t < T_HOR; ++t) { ua[t] = ck0[t]; ub[t] = ck1[t]; }
                #pragma unroll 1
                for (int j = 0; j <= jj; ++j)
                    iter_once(c0, c1, gp, hp, xi_p, xi_v, pc_p, pc_v, ua, ub);
                break;   // gmt is grid-uniform -> uniform break, no divergent sync
            }
            it_base += gl;
        }
    }

    // out element b = [s0.ua, s0.ub, s1.ua, s1.ub] -> float2 slot 2b+s == tid
    out[tid] = make_float2(ua[0], ub[0]);
}

extern "C" void kernel_launch(void* const* d_in, const int* in_sizes, int n_in,
                              void* d_out, int out_size, void* d_ws, size_t ws_size,
                              hipStream_t stream) {
    const float* x_init = (const float*)d_in[0];
    const float* xd     = (const float*)d_in[1];
    float2* out         = (float2*)d_out;
    int* flags          = (int*)d_ws;

    const int B = in_sizes[0] / 4;          // 65536
    const int threads = 2 * B;              // one thread per subsystem
    int g0len = 32, glen = 8;               // n* known in (32,48] from R2 trace
    void* args[] = { (void*)&x_init, (void*)&xd, (void*)&out, (void*)&flags,
                     (void*)&g0len, (void*)&glen };
    dim3 grid(threads / 256), block(256);
    hipLaunchCooperativeKernel((const void*)mpc_iter_kernel, grid, block, args, 0, stream);
}

// Round 6
// 103.618 us; speedup vs baseline: 1.3810x; 1.3810x over previous
//
#include <hip/hip_runtime.h>
#include <hip/hip_cooperative_groups.h>

namespace cg = cooperative_groups;

#define T_HOR 5
#define MAXIT 100
#define G0    32                  // first group: 32 iterations (n* known in (32,48])
#define GT    4                   // tail groups of 4
#define NFLAGS 18                 // 1 + ceil((100-32)/4)
#define EPSC  0.01f

// ===== EXACT R2 body (proven 0.66 us/iter codegen) — do not modify =====
// One LQR sweep for one batch element (two decoupled 2-state subsystems).
// Returns max |du| over all controls/timesteps.
__device__ __forceinline__ float iter_once(
    const float (&c0)[T_HOR], const float (&c1)[T_HOR],
    const float (&gp)[T_HOR], const float (&hp)[T_HOR],
    float xi0, float xi1, float xi2, float xi3,
    float pc_p1, float pc_v1, float pc_p2, float pc_v2,
    float (&ua1)[T_HOR], float (&ub1)[T_HOR],
    float (&ua2)[T_HOR], float (&ub2)[T_HOR])
{
    // rollout
    float xp1[T_HOR], xv1[T_HOR], xp2[T_HOR], xv2[T_HOR];
    xp1[0] = xi0; xp2[0] = xi1; xv1[0] = xi2; xv2[0] = xi3;
    #pragma unroll
    for (int t = 0; t < T_HOR-1; ++t) {
        xp1[t+1] = xp1[t] + 0.1f*xv1[t];
        xv1[t+1] = 0.75f*xv1[t] + 0.5f*(ua1[t]-ub1[t]);
        xp2[t+1] = xp2[t] + 0.1f*xv2[t];
        xv2[t+1] = 0.75f*xv2[t] + 0.5f*(ua2[t]-ub2[t]);
    }

    // backward affine pass
    float ka1[T_HOR], kb1[T_HOR], ka2[T_HOR], kb2[T_HOR];
    float v1p = 0.f, v1v = 0.f, v2p = 0.f, v2v = 0.f;
    #pragma unroll
    for (int t = T_HOR-1; t >= 0; --t) {
        float qa = 0.01f + 0.1f*ua1[t] + 0.5f*v1v;
        float qb = 0.01f + 0.1f*ub1[t] - 0.5f*v1v;
        ka1[t] = -(c0[t]*qa + c1[t]*qb);
        kb1[t] = -(c1[t]*qa + c0[t]*qb);
        float qxp = (pc_p1 + xp1[t]) + v1p;
        float qxv = (pc_v1 + 0.1f*xv1[t]) + 0.1f*v1p + 0.75f*v1v;
        float dq = qa - qb;
        v1p = qxp - gp[t]*dq;
        v1v = qxv - hp[t]*dq;

        float qa2 = 0.01f + 0.1f*ua2[t] + 0.5f*v2v;
        float qb2 = 0.01f + 0.1f*ub2[t] - 0.5f*v2v;
        ka2[t] = -(c0[t]*qa2 + c1[t]*qb2);
        kb2[t] = -(c1[t]*qa2 + c0[t]*qb2);
        float qxp2 = (pc_p2 + xp2[t]) + v2p;
        float qxv2 = (pc_v2 + 0.1f*xv2[t]) + 0.1f*v2p + 0.75f*v2v;
        float dq2 = qa2 - qb2;
        v2p = qxp2 - gp[t]*dq2;
        v2v = qxv2 - hp[t]*dq2;
    }

    // forward pass with clip
    float delta = 0.f;
    float d1p = 0.f, d1v = 0.f, d2p = 0.f, d2v = 0.f;
    #pragma unroll
    for (int t = 0; t < T_HOR; ++t) {
        float phi1 = gp[t]*d1p + hp[t]*d1v;
        float na = fminf(fmaxf(ua1[t] + (ka1[t] - phi1), 0.f), 1.f);
        float nb = fminf(fmaxf(ub1[t] + (kb1[t] + phi1), 0.f), 1.f);
        float dua = na - ua1[t], dub = nb - ub1[t];
        delta = fmaxf(delta, fmaxf(fabsf(dua), fabsf(dub)));
        float n1p = d1p + 0.1f*d1v;
        float n1v = 0.75f*d1v + 0.5f*(dua - dub);
        d1p = n1p; d1v = n1v;
        ua1[t] = na; ub1[t] = nb;

        float phi2 = gp[t]*d2p + hp[t]*d2v;
        float na2 = fminf(fmaxf(ua2[t] + (ka2[t] - phi2), 0.f), 1.f);
        float nb2 = fminf(fmaxf(ub2[t] + (kb2[t] + phi2), 0.f), 1.f);
        float dua2 = na2 - ua2[t], dub2 = nb2 - ub2[t];
        delta = fmaxf(delta, fmaxf(fabsf(dua2), fabsf(dub2)));
        float n2p = d2p + 0.1f*d2v;
        float n2v = 0.75f*d2v + 0.5f*(dua2 - dub2);
        d2p = n2p; d2v = n2v;
        ua2[t] = na2; ub2[t] = nb2;
    }
    return delta;
}

__global__ __launch_bounds__(256)
void mpc_iter_kernel(const float4* __restrict__ x_init,
                     const float4* __restrict__ xd,
                     float4* __restrict__ out,
                     int* __restrict__ flags)
{
    cg::grid_group grid = cg::this_grid();
    const int b = blockIdx.x * 256 + threadIdx.x;

    // in-kernel workspace zeroing; visible grid-wide at the first grid.sync
    if (b == 0) {
        #pragma unroll
        for (int g = 0; g < NFLAGS; ++g) flags[g] = 0;
    }

    const float4 xi  = x_init[b];   // [p1, p2, v1, v2]
    const float4 xdv = xd[b];
    const float SQ01 = 0.31622776601683794f;
    const float pc_p1 = -xdv.x;
    const float pc_p2 = -xdv.y;
    const float pc_v1 = -SQ01 * xdv.z;
    const float pc_v2 = -SQ01 * xdv.w;

    // Batch-independent Riccati gain schedule (constant-folds at compile time)
    float c0[T_HOR], c1[T_HOR], gp[T_HOR], hp[T_HOR];
    {
        float Vpp = 0.f, Vpv = 0.f, Vvv = 0.f;
        #pragma unroll
        for (int t = T_HOR-1; t >= 0; --t) {
            float s  = 0.25f * Vvv;
            float tw = 0.1f + 2.f*s;
            float dd = 0.1f * tw;
            c0[t] = (0.1f + s) / dd;
            c1[t] = s / dd;
            float g = 0.5f * Vpv;
            float h = 0.05f * Vpv + 0.375f * Vvv;
            float inv = 1.f / tw;
            gp[t] = g * inv;
            hp[t] = h * inv;
            float nVpp = 1.0f + Vpp - 2.f*g*gp[t];
            float nVpv = 0.1f*Vpp + 0.75f*Vpv - 2.f*g*hp[t];
            float nVvv = 0.1f + 0.01f*Vpp + 0.15f*Vpv + 0.5625f*Vvv - 2.f*h*hp[t];
            Vpp = nVpp; Vpv = nVpv; Vvv = nVvv;
        }
    }

    float ua1[T_HOR] = {0,0,0,0,0}, ub1[T_HOR] = {0,0,0,0,0};
    float ua2[T_HOR] = {0,0,0,0,0}, ub2[T_HOR] = {0,0,0,0,0};

    // ---- group 0: G0 iterations, convergence bitmask, 2 syncs
    unsigned mask = 0u;
    for (int j = 0; j < G0; ++j) {
        float d = iter_once(c0, c1, gp, hp, xi.x, xi.y, xi.z, xi.w,
                            pc_p1, pc_v1, pc_p2, pc_v2,
                            ua1, ub1, ua2, ub2);
        mask |= (d > EPSC ? 1u : 0u) << j;
    }
    int bor = __syncthreads_or((int)mask);
    grid.sync();   // flag zeroing visible before any atomicOr
    if (threadIdx.x == 0 && bor) {
        __hip_atomic_fetch_or(&flags[0], bor, __ATOMIC_RELEASE, __HIP_MEMORY_SCOPE_AGENT);
    }
    grid.sync();
    unsigned gm = (unsigned)__hip_atomic_load(&flags[0], __ATOMIC_ACQUIRE, __HIP_MEMORY_SCOPE_AGENT);
    unsigned ngm = ~gm;
    int j0 = ngm ? (int)__builtin_ctz(ngm) : 32;   // guard: all-32-set would be ctz(0)=UB

    bool done = false;
    if (j0 < G0) {
        // cold path (n* <= G0): replay j0+1 iterations from zeros
        #pragma unroll
        for (int t = 0; t < T_HOR; ++t) { ua1[t]=0.f; ub1[t]=0.f; ua2[t]=0.f; ub2[t]=0.f; }
        for (int j = 0; j <= j0; ++j)
            iter_once(c0, c1, gp, hp, xi.x, xi.y, xi.z, xi.w,
                      pc_p1, pc_v1, pc_p2, pc_v2, ua1, ub1, ua2, ub2);
        done = true;
    }

    // ---- tail: groups of GT, checkpoint + one sync + replay on stop (R2 structure)
    if (!done) {
        int it_base = G0;
        for (int g = 1; it_base < MAXIT; ++g) {
            const int gl = (MAXIT - it_base < GT) ? (MAXIT - it_base) : GT;
            float ck0[T_HOR], ck1[T_HOR], ck2[T_HOR], ck3[T_HOR];
            #pragma unroll
            for (int t = 0; t < T_HOR; ++t) {
                ck0[t]=ua1[t]; ck1[t]=ub1[t]; ck2[t]=ua2[t]; ck3[t]=ub2[t];
            }

            unsigned msk = 0u;
            for (int j = 0; j < gl; ++j) {
                float d = iter_once(c0, c1, gp, hp, xi.x, xi.y, xi.z, xi.w,
                                    pc_p1, pc_v1, pc_p2, pc_v2,
                                    ua1, ub1, ua2, ub2);
                msk |= (d > EPSC ? 1u : 0u) << j;
            }
            int m = __syncthreads_or((int)msk);
            if (threadIdx.x == 0 && m) {
                __hip_atomic_fetch_or(&flags[g], m, __ATOMIC_RELEASE, __HIP_MEMORY_SCOPE_AGENT);
            }
            grid.sync();
            unsigned gmt = (unsigned)__hip_atomic_load(&flags[g], __ATOMIC_ACQUIRE, __HIP_MEMORY_SCOPE_AGENT);
            int jj = (int)__builtin_ctz(~gmt);   // bits >= gl are 0 -> jj <= gl, ~gmt != 0
            if (jj < gl) {
                // global stop at iteration it_base+jj+1: restore + replay
                #pragma unroll
                for (int t = 0; t < T_HOR; ++t) {
                    ua1[t]=ck0[t]; ub1[t]=ck1[t]; ua2[t]=ck2[t]; ub2[t]=ck3[t];
                }
                for (int j = 0; j <= jj; ++j)
                    iter_once(c0, c1, gp, hp, xi.x, xi.y, xi.z, xi.w,
                              pc_p1, pc_v1, pc_p2, pc_v2, ua1, ub1, ua2, ub2);
                break;   // gmt grid-uniform -> uniform break
            }
            it_base += gl;
        }
    }

    out[b] = make_float4(ua1[0], ub1[0], ua2[0], ub2[0]);
}

extern "C" void kernel_launch(void* const* d_in, const int* in_sizes, int n_in,
                              void* d_out, int out_size, void* d_ws, size_t ws_size,
                              hipStream_t stream) {
    const float4* x_init = (const float4*)d_in[0];
    const float4* xd     = (const float4*)d_in[1];
    float4* out          = (float4*)d_out;
    int* flags           = (int*)d_ws;

    const int B = in_sizes[0] / 4;          // 65536
    void* args[] = { (void*)&x_init, (void*)&xd, (void*)&out, (void*)&flags };
    dim3 grid(B / 256), block(256);
    hipLaunchCooperativeKernel((const void*)mpc_iter_kernel, grid, block, args, 0, stream);
}

// Round 7
// 74.389 us; speedup vs baseline: 1.9236x; 1.3929x over previous
//
#include <hip/hip_runtime.h>
#include <hip/hip_cooperative_groups.h>

namespace cg = cooperative_groups;

#define T_HOR 5
#define MAXIT 100
#define NFLAGS 20
#define EPSC  0.01f

// ===== EXACT R2 body (proven 0.71 us/iter codegen) — do not modify =====
// One LQR sweep for one batch element (two decoupled 2-state subsystems).
// Returns max |du| over all controls/timesteps.
__device__ __forceinline__ float iter_once(
    const float (&c0)[T_HOR], const float (&c1)[T_HOR],
    const float (&gp)[T_HOR], const float (&hp)[T_HOR],
    float xi0, float xi1, float xi2, float xi3,
    float pc_p1, float pc_v1, float pc_p2, float pc_v2,
    float (&ua1)[T_HOR], float (&ub1)[T_HOR],
    float (&ua2)[T_HOR], float (&ub2)[T_HOR])
{
    // rollout
    float xp1[T_HOR], xv1[T_HOR], xp2[T_HOR], xv2[T_HOR];
    xp1[0] = xi0; xp2[0] = xi1; xv1[0] = xi2; xv2[0] = xi3;
    #pragma unroll
    for (int t = 0; t < T_HOR-1; ++t) {
        xp1[t+1] = xp1[t] + 0.1f*xv1[t];
        xv1[t+1] = 0.75f*xv1[t] + 0.5f*(ua1[t]-ub1[t]);
        xp2[t+1] = xp2[t] + 0.1f*xv2[t];
        xv2[t+1] = 0.75f*xv2[t] + 0.5f*(ua2[t]-ub2[t]);
    }

    // backward affine pass
    float ka1[T_HOR], kb1[T_HOR], ka2[T_HOR], kb2[T_HOR];
    float v1p = 0.f, v1v = 0.f, v2p = 0.f, v2v = 0.f;
    #pragma unroll
    for (int t = T_HOR-1; t >= 0; --t) {
        float qa = 0.01f + 0.1f*ua1[t] + 0.5f*v1v;
        float qb = 0.01f + 0.1f*ub1[t] - 0.5f*v1v;
        ka1[t] = -(c0[t]*qa + c1[t]*qb);
        kb1[t] = -(c1[t]*qa + c0[t]*qb);
        float qxp = (pc_p1 + xp1[t]) + v1p;
        float qxv = (pc_v1 + 0.1f*xv1[t]) + 0.1f*v1p + 0.75f*v1v;
        float dq = qa - qb;
        v1p = qxp - gp[t]*dq;
        v1v = qxv - hp[t]*dq;

        float qa2 = 0.01f + 0.1f*ua2[t] + 0.5f*v2v;
        float qb2 = 0.01f + 0.1f*ub2[t] - 0.5f*v2v;
        ka2[t] = -(c0[t]*qa2 + c1[t]*qb2);
        kb2[t] = -(c1[t]*qa2 + c0[t]*qb2);
        float qxp2 = (pc_p2 + xp2[t]) + v2p;
        float qxv2 = (pc_v2 + 0.1f*xv2[t]) + 0.1f*v2p + 0.75f*v2v;
        float dq2 = qa2 - qb2;
        v2p = qxp2 - gp[t]*dq2;
        v2v = qxv2 - hp[t]*dq2;
    }

    // forward pass with clip
    float delta = 0.f;
    float d1p = 0.f, d1v = 0.f, d2p = 0.f, d2v = 0.f;
    #pragma unroll
    for (int t = 0; t < T_HOR; ++t) {
        float phi1 = gp[t]*d1p + hp[t]*d1v;
        float na = fminf(fmaxf(ua1[t] + (ka1[t] - phi1), 0.f), 1.f);
        float nb = fminf(fmaxf(ub1[t] + (kb1[t] + phi1), 0.f), 1.f);
        float dua = na - ua1[t], dub = nb - ub1[t];
        delta = fmaxf(delta, fmaxf(fabsf(dua), fabsf(dub)));
        float n1p = d1p + 0.1f*d1v;
        float n1v = 0.75f*d1v + 0.5f*(dua - dub);
        d1p = n1p; d1v = n1v;
        ua1[t] = na; ub1[t] = nb;

        float phi2 = gp[t]*d2p + hp[t]*d2v;
        float na2 = fminf(fmaxf(ua2[t] + (ka2[t] - phi2), 0.f), 1.f);
        float nb2 = fminf(fmaxf(ub2[t] + (kb2[t] + phi2), 0.f), 1.f);
        float dua2 = na2 - ua2[t], dub2 = nb2 - ub2[t];
        delta = fmaxf(delta, fmaxf(fabsf(dua2), fabsf(dub2)));
        float n2p = d2p + 0.1f*d2v;
        float n2v = 0.75f*d2v + 0.5f*(dua2 - dub2);
        d2p = n2p; d2v = n2v;
        ua2[t] = na2; ub2[t] = nb2;
    }
    return delta;
}

__global__ __launch_bounds__(256)
void mpc_iter_kernel(const float4* __restrict__ x_init,
                     const float4* __restrict__ xd,
                     float4* __restrict__ out,
                     int* __restrict__ gmask,
                     int g0len, int glen)   // RUNTIME group lengths -> loops stay rolled
{
    cg::grid_group grid = cg::this_grid();
    const int b = blockIdx.x * 256 + threadIdx.x;

    const float4 xi  = x_init[b];   // [p1, p2, v1, v2]
    const float4 xdv = xd[b];
    const float SQ01 = 0.31622776601683794f;
    const float pc_p1 = -xdv.x;
    const float pc_p2 = -xdv.y;
    const float pc_v1 = -SQ01 * xdv.z;
    const float pc_v2 = -SQ01 * xdv.w;

    // Batch-independent Riccati gain schedule (constant-folds at compile time)
    float c0[T_HOR], c1[T_HOR], gp[T_HOR], hp[T_HOR];
    {
        float Vpp = 0.f, Vpv = 0.f, Vvv = 0.f;
        #pragma unroll
        for (int t = T_HOR-1; t >= 0; --t) {
            float s  = 0.25f * Vvv;
            float tw = 0.1f + 2.f*s;
            float dd = 0.1f * tw;
            c0[t] = (0.1f + s) / dd;
            c1[t] = s / dd;
            float g = 0.5f * Vpv;
            float h = 0.05f * Vpv + 0.375f * Vvv;
            float inv = 1.f / tw;
            gp[t] = g * inv;
            hp[t] = h * inv;
            float nVpp = 1.0f + Vpp - 2.f*g*gp[t];
            float nVpv = 0.1f*Vpp + 0.75f*Vpv - 2.f*g*hp[t];
            float nVvv = 0.1f + 0.01f*Vpp + 0.15f*Vpv + 0.5625f*Vvv - 2.f*h*hp[t];
            Vpp = nVpp; Vpv = nVpv; Vvv = nVvv;
        }
    }

    float ua1[T_HOR] = {0,0,0,0,0}, ub1[T_HOR] = {0,0,0,0,0};
    float ua2[T_HOR] = {0,0,0,0,0}, ub2[T_HOR] = {0,0,0,0,0};

    // ---- group 0: g0len iterations (runtime bound), one sync (R2 mechanics)
    unsigned mask = 0u;
    for (int j = 0; j < g0len; ++j) {
        float d = iter_once(c0, c1, gp, hp, xi.x, xi.y, xi.z, xi.w,
                            pc_p1, pc_v1, pc_p2, pc_v2,
                            ua1, ub1, ua2, ub2);
        mask |= (d > EPSC ? 1u : 0u) << j;
    }
    int m0 = __syncthreads_or((int)mask);
    if (threadIdx.x == 0 && m0) {
        __hip_atomic_fetch_or(&gmask[0], m0, __ATOMIC_RELEASE, __HIP_MEMORY_SCOPE_AGENT);
    }
    grid.sync();
    unsigned gm = (unsigned)__hip_atomic_load(&gmask[0], __ATOMIC_ACQUIRE, __HIP_MEMORY_SCOPE_AGENT);
    unsigned ngm = ~gm;
    int j0 = ngm ? (int)__builtin_ctz(ngm) : 32;   // guard full mask (g0len==32)

    bool done = false;
    if (j0 < g0len) {
        // cold path (n* <= g0len): replay j0+1 iterations from zeros
        #pragma unroll
        for (int t = 0; t < T_HOR; ++t) { ua1[t]=0.f; ub1[t]=0.f; ua2[t]=0.f; ub2[t]=0.f; }
        for (int j = 0; j <= j0; ++j)
            iter_once(c0, c1, gp, hp, xi.x, xi.y, xi.z, xi.w,
                      pc_p1, pc_v1, pc_p2, pc_v2, ua1, ub1, ua2, ub2);
        done = true;
    }

    // ---- tail: groups of glen (runtime), checkpoint + one sync + replay on stop
    if (!done) {
        int it_base = g0len;
        for (int g = 1; it_base < MAXIT; ++g) {
            const int gl = (MAXIT - it_base < glen) ? (MAXIT - it_base) : glen;
            float ck0[T_HOR], ck1[T_HOR], ck2[T_HOR], ck3[T_HOR];
            #pragma unroll
            for (int t = 0; t < T_HOR; ++t) {
                ck0[t]=ua1[t]; ck1[t]=ub1[t]; ck2[t]=ua2[t]; ck3[t]=ub2[t];
            }

            unsigned msk = 0u;
            for (int j = 0; j < gl; ++j) {
                float d = iter_once(c0, c1, gp, hp, xi.x, xi.y, xi.z, xi.w,
                                    pc_p1, pc_v1, pc_p2, pc_v2,
                                    ua1, ub1, ua2, ub2);
                msk |= (d > EPSC ? 1u : 0u) << j;
            }
            int m = __syncthreads_or((int)msk);
            if (threadIdx.x == 0 && m) {
                __hip_atomic_fetch_or(&gmask[g], m, __ATOMIC_RELEASE, __HIP_MEMORY_SCOPE_AGENT);
            }
            grid.sync();
            unsigned gmt = (unsigned)__hip_atomic_load(&gmask[g], __ATOMIC_ACQUIRE, __HIP_MEMORY_SCOPE_AGENT);
            int jj = (int)__builtin_ctz(~gmt);   // bits >= gl are 0 -> jj <= gl, ~gmt != 0
            if (jj < gl) {
                // global stop at iteration it_base+jj+1: restore + replay
                #pragma unroll
                for (int t = 0; t < T_HOR; ++t) {
                    ua1[t]=ck0[t]; ub1[t]=ck1[t]; ua2[t]=ck2[t]; ub2[t]=ck3[t];
                }
                for (int j = 0; j <= jj; ++j)
                    iter_once(c0, c1, gp, hp, xi.x, xi.y, xi.z, xi.w,
                              pc_p1, pc_v1, pc_p2, pc_v2, ua1, ub1, ua2, ub2);
                break;   // gmt grid-uniform -> uniform break
            }
            it_base += gl;
        }
    }

    out[b] = make_float4(ua1[0], ub1[0], ua2[0], ub2[0]);
}

extern "C" void kernel_launch(void* const* d_in, const int* in_sizes, int n_in,
                              void* d_out, int out_size, void* d_ws, size_t ws_size,
                              hipStream_t stream) {
    const float4* x_init = (const float4*)d_in[0];
    const float4* xd     = (const float4*)d_in[1];
    float4* out          = (float4*)d_out;
    int* gmask           = (int*)d_ws;

    const int B = in_sizes[0] / 4;          // 65536
    hipMemsetAsync(d_ws, 0, NFLAGS * sizeof(int), stream);

    int g0len = 32, glen = 4;               // n* known in (32,48] from R2 trace
    void* args[] = { (void*)&x_init, (void*)&xd, (void*)&out, (void*)&gmask,
                     (void*)&g0len, (void*)&glen };
    dim3 grid(B / 256), block(256);
    hipLaunchCooperativeKernel((const void*)mpc_iter_kernel, grid, block, args, 0, stream);
}